// Round 1
// baseline (1412.686 us; speedup 1.0000x reference)
//
#include <hip/hip_runtime.h>
#include <hip/hip_bf16.h>

#define B_ 8192
#define D_ 512
#define M_ 1000
#define H_ 8
#define DH_ 64
#define XD_ 528   // D + 16

static inline int cdiv(int a, int b) { return (a + b - 1) / b; }

__device__ inline float wave_sum(float v) {
#pragma unroll
    for (int off = 32; off > 0; off >>= 1) v += __shfl_xor(v, off);
    return v;
}
__device__ inline float wave_max(float v) {
#pragma unroll
    for (int off = 32; off > 0; off >>= 1) v = fmaxf(v, __shfl_xor(v, off));
    return v;
}

// C[m,n] = epilogue( sum_k A[m,k] * B'[n,k] + bias[n] )
// TRANSB=true : Bm is [N,K] row-major (weight layout, C = A @ W^T)
// TRANSB=false: Bm is [K,N] row-major (C = A @ B)
// RELU: relu after bias. COMBINE: out = c0*E[m,n] + c1*(val+bias)
// Batched over blockIdx.z with element strides sA/sB/sC (E shares sC/ldc).
template<bool TRANSB, bool RELU, bool COMBINE>
__launch_bounds__(256)
__global__ void gemm_kernel(const float* __restrict__ A,
                            const float* __restrict__ Bm,
                            const float* __restrict__ bias,
                            const float* __restrict__ E,
                            float* __restrict__ C,
                            int M, int N, int K,
                            int lda, int ldb, int ldc,
                            long long sA, long long sB, long long sC,
                            float c0, float c1)
{
    const int z = blockIdx.z;
    A  += z * sA;
    Bm += z * sB;
    C  += z * sC;
    const float* Ep = nullptr;
    if (COMBINE) Ep = E + z * sC;

    const int m0 = blockIdx.y * 128;
    const int n0 = blockIdx.x * 64;
    const int t  = threadIdx.x;

    __shared__ float As[16][128];
    __shared__ float Bs[16][64];

    const int tn = (t & 15) * 4;   // 0..60
    const int tm = (t >> 4) * 8;   // 0..120

    float acc[8][4];
#pragma unroll
    for (int i = 0; i < 8; ++i)
#pragma unroll
        for (int j = 0; j < 4; ++j) acc[i][j] = 0.0f;

    for (int k0 = 0; k0 < K; k0 += 16) {
        // ---- stage A tile (128 rows x 16 k), transposed into As[k][m]
#pragma unroll
        for (int i = 0; i < 2; ++i) {
            const int f  = t + i * 256;      // 0..511
            const int r  = f >> 2;           // 0..127
            const int c4 = (f & 3) * 4;      // 0,4,8,12
            const int gm = m0 + r;
            const int gk = k0 + c4;
            float4 v = make_float4(0.f, 0.f, 0.f, 0.f);
            if (gm < M) {
                const float* ap = A + (long long)gm * lda + gk;
                if (gk + 3 < K) {
                    v = *(const float4*)ap;
                } else {
                    if (gk + 0 < K) v.x = ap[0];
                    if (gk + 1 < K) v.y = ap[1];
                    if (gk + 2 < K) v.z = ap[2];
                }
            }
            As[c4 + 0][r] = v.x;
            As[c4 + 1][r] = v.y;
            As[c4 + 2][r] = v.z;
            As[c4 + 3][r] = v.w;
        }
        // ---- stage B tile
        if (TRANSB) {
            // Bm[N,K]: 64 rows x 16 k, transposed into Bs[k][n]
            const int r  = t >> 2;           // 0..63
            const int c4 = (t & 3) * 4;
            const int gn = n0 + r;
            const int gk = k0 + c4;
            float4 v = make_float4(0.f, 0.f, 0.f, 0.f);
            if (gn < N) {
                const float* bp = Bm + (long long)gn * ldb + gk;
                if (gk + 3 < K) {
                    v = *(const float4*)bp;
                } else {
                    if (gk + 0 < K) v.x = bp[0];
                    if (gk + 1 < K) v.y = bp[1];
                    if (gk + 2 < K) v.z = bp[2];
                }
            }
            Bs[c4 + 0][r] = v.x;
            Bs[c4 + 1][r] = v.y;
            Bs[c4 + 2][r] = v.z;
            Bs[c4 + 3][r] = v.w;
        } else {
            // Bm[K,N]: 16 k x 64 n, direct into Bs[k][n]
            const int r  = t >> 4;           // 0..15
            const int c4 = (t & 15) * 4;     // 0..60
            const int gk = k0 + r;
            const int gn = n0 + c4;
            float4 v = make_float4(0.f, 0.f, 0.f, 0.f);
            if (gk < K) {
                const float* bp = Bm + (long long)gk * ldb + gn;
                if (gn + 3 < N) {
                    v = *(const float4*)bp;
                } else {
                    if (gn + 0 < N) v.x = bp[0];
                    if (gn + 1 < N) v.y = bp[1];
                    if (gn + 2 < N) v.z = bp[2];
                }
            }
            *(float4*)&Bs[r][c4] = v;
        }
        __syncthreads();

#pragma unroll
        for (int kk = 0; kk < 16; ++kk) {
            const float4 b4 = *(const float4*)&Bs[kk][tn];
            const float4 a0 = *(const float4*)&As[kk][tm];
            const float4 a1 = *(const float4*)&As[kk][tm + 4];
            const float av[8] = {a0.x, a0.y, a0.z, a0.w, a1.x, a1.y, a1.z, a1.w};
            const float bv[4] = {b4.x, b4.y, b4.z, b4.w};
#pragma unroll
            for (int i = 0; i < 8; ++i)
#pragma unroll
                for (int j = 0; j < 4; ++j)
                    acc[i][j] = fmaf(av[i], bv[j], acc[i][j]);
        }
        __syncthreads();
    }

    // ---- epilogue
#pragma unroll
    for (int i = 0; i < 8; ++i) {
        const int gm = m0 + tm + i;
        if (gm >= M) continue;
#pragma unroll
        for (int j = 0; j < 4; ++j) {
            const int gn = n0 + tn + j;
            if (gn >= N) continue;
            float v = acc[i][j];
            if (bias) v += bias[gn];
            if (RELU) v = fmaxf(v, 0.0f);
            if (COMBINE) v = c0 * Ep[(long long)gm * ldc + gn] + c1 * v;
            C[(long long)gm * ldc + gn] = v;
        }
    }
}

// rowwise LayerNorm in place, rows of length 512; one wave per row
__global__ void layernorm_kernel(float* __restrict__ X,
                                 const float* __restrict__ g,
                                 const float* __restrict__ be,
                                 int rows)
{
    const int row  = blockIdx.x * 4 + (threadIdx.x >> 6);
    const int lane = threadIdx.x & 63;
    if (row >= rows) return;
    float* p = X + (long long)row * D_ + lane * 8;
    float4 x0 = *(const float4*)p;
    float4 x1 = *(const float4*)(p + 4);
    float v[8] = {x0.x, x0.y, x0.z, x0.w, x1.x, x1.y, x1.z, x1.w};
    float s = 0.f;
#pragma unroll
    for (int i = 0; i < 8; ++i) s += v[i];
    s = wave_sum(s);
    const float mu = s * (1.0f / 512.0f);
    float vs = 0.f;
#pragma unroll
    for (int i = 0; i < 8; ++i) { v[i] -= mu; vs += v[i] * v[i]; }
    vs = wave_sum(vs);
    const float r = rsqrtf(vs * (1.0f / 512.0f) + 1e-5f);
    const float* gp = g  + lane * 8;
    const float* bp = be + lane * 8;
    float o[8];
#pragma unroll
    for (int i = 0; i < 8; ++i) o[i] = v[i] * r * gp[i] + bp[i];
    *(float4*)p       = make_float4(o[0], o[1], o[2], o[3]);
    *(float4*)(p + 4) = make_float4(o[4], o[5], o[6], o[7]);
}

// softmax over rows of length 1000 (applies *0.125 scale), layout:
// row rid -> base (rid/8)*8000 + (rid%8)*1000. one wave per row, in place.
__global__ void softmax_kernel(float* __restrict__ S, int nrows)
{
    const int rid  = blockIdx.x * 4 + (threadIdx.x >> 6);
    const int lane = threadIdx.x & 63;
    if (rid >= nrows) return;
    float* p = S + (long long)(rid >> 3) * 8000 + (long long)(rid & 7) * 1000;
    float v[16];
    float mx = -1e30f;
#pragma unroll
    for (int i = 0; i < 16; ++i) {
        const int m = lane + i * 64;
        v[i] = (m < M_) ? p[m] * 0.125f : -1e30f;
        mx = fmaxf(mx, v[i]);
    }
    mx = wave_max(mx);
    float sum = 0.f;
#pragma unroll
    for (int i = 0; i < 16; ++i) {
        const int m = lane + i * 64;
        if (m < M_) { v[i] = expf(v[i] - mx); sum += v[i]; }
    }
    sum = wave_sum(sum);
    const float inv = 1.0f / sum;
#pragma unroll
    for (int i = 0; i < 16; ++i) {
        const int m = lane + i * 64;
        if (m < M_) p[m] = v[i] * inv;
    }
}

// x = concat(fused[B,512], ego[B,16]) -> X[B,528]
__global__ void concat_kernel(const float* __restrict__ fused,
                              const float* __restrict__ ego,
                              float* __restrict__ X)
{
    const int i = blockIdx.x * 256 + threadIdx.x;
    if (i >= B_ * XD_) return;
    const int b = i / XD_;
    const int c = i - b * XD_;
    X[i] = (c < D_) ? fused[(long long)b * D_ + c] : ego[b * 16 + (c - D_)];
}

// quality[b] = sigmoid( dot(qh[b,:128], w2) + b2 ); one wave per row
__global__ void quality_kernel(const float* __restrict__ qh,
                               const float* __restrict__ w2,
                               const float* __restrict__ b2,
                               float* __restrict__ outq, int rows)
{
    const int row  = blockIdx.x * 4 + (threadIdx.x >> 6);
    const int lane = threadIdx.x & 63;
    if (row >= rows) return;
    const float* p = qh + (long long)row * 128;
    float s = p[lane] * w2[lane] + p[64 + lane] * w2[64 + lane];
    s = wave_sum(s);
    if (lane == 0) outq[row] = 1.0f / (1.0f + expf(-(s + b2[0])));
}

// ordered compaction of {b : quality[b] > 0.7} -> list, count. single block.
__global__ void compact_kernel(const float* __restrict__ q,
                               int* __restrict__ list, int* __restrict__ cnt)
{
    __shared__ int wtot[16];
    __shared__ int sbase;
    const int t = threadIdx.x, w = t >> 6, lane = t & 63;
    if (t == 0) sbase = 0;
    __syncthreads();
    for (int c = 0; c < B_; c += 1024) {
        const int idx = c + t;
        const bool pred = (q[idx] > 0.7f);
        const unsigned long long bal = __ballot(pred);
        const int prefix = __popcll(bal & ((1ull << lane) - 1ull));
        if (lane == 0) wtot[w] = __popcll(bal);
        __syncthreads();
        int woff = 0;
        for (int i = 0; i < w; ++i) woff += wtot[i];
        if (pred) list[sbase + woff + prefix] = idx;
        __syncthreads();
        if (t == 0) {
            int tot = 0;
            for (int i = 0; i < 16; ++i) tot += wtot[i];
            sbase += tot;
        }
        __syncthreads();
    }
    if (t == 0) *cnt = sbase;
}

// scatter-EMA: one block per memory row; apply ordered updates
__global__ void update_memory_kernel(const float* __restrict__ mem,
                                     const float* __restrict__ ns,
                                     const int* __restrict__ upd,
                                     const int* __restrict__ list,
                                     const int* __restrict__ cnt,
                                     float* __restrict__ outmem)
{
    const int m = blockIdx.x;      // 0..999
    const int t = threadIdx.x;     // 0..127
    const int c4 = t * 4;
    float4 r = *(const float4*)(mem + (long long)m * D_ + c4);
    const int n = *cnt;
    for (int i = 0; i < n; ++i) {
        const int b = list[i];
        if (upd[b] == m) {
            const float4 s = *(const float4*)(ns + (long long)b * D_ + c4);
            r.x = 0.9f * r.x + 0.1f * s.x;
            r.y = 0.9f * r.y + 0.1f * s.y;
            r.z = 0.9f * r.z + 0.1f * s.z;
            r.w = 0.9f * r.w + 0.1f * s.w;
        }
    }
    *(float4*)(outmem + (long long)m * D_ + c4) = r;
}

extern "C" void kernel_launch(void* const* d_in, const int* in_sizes, int n_in,
                              void* d_out, int out_size, void* d_ws, size_t ws_size,
                              hipStream_t stream)
{
    const float* obs    = (const float*)d_in[0];
    const float* ego    = (const float*)d_in[1];
    const float* wmem   = (const float*)d_in[2];
    const float* enc_w1 = (const float*)d_in[3];
    const float* enc_b1 = (const float*)d_in[4];
    const float* enc_g  = (const float*)d_in[5];
    const float* enc_be = (const float*)d_in[6];
    const float* enc_w2 = (const float*)d_in[7];
    const float* enc_b2 = (const float*)d_in[8];
    const float* wq = (const float*)d_in[9];
    const float* bq = (const float*)d_in[10];
    const float* wk = (const float*)d_in[11];
    const float* bk = (const float*)d_in[12];
    const float* wv = (const float*)d_in[13];
    const float* bvv = (const float*)d_in[14];
    const float* wo = (const float*)d_in[15];
    const float* bo = (const float*)d_in[16];
    const float* tr_w1 = (const float*)d_in[17];
    const float* tr_b1 = (const float*)d_in[18];
    const float* tr_g  = (const float*)d_in[19];
    const float* tr_be = (const float*)d_in[20];
    const float* tr_w2 = (const float*)d_in[21];
    const float* tr_b2 = (const float*)d_in[22];
    const float* q_w1 = (const float*)d_in[23];
    const float* q_b1 = (const float*)d_in[24];
    const float* q_w2 = (const float*)d_in[25];
    const float* q_b2 = (const float*)d_in[26];
    const int*   upd  = (const int*)d_in[27];

    float* out_ns  = (float*)d_out;
    float* out_q   = out_ns + (size_t)B_ * D_;
    float* out_mem = out_q + B_;

    float* ws = (float*)d_ws;
    size_t p = 0;
    float* Abuf = ws + p; p += (size_t)B_ * D_;    // h/hn -> ctx -> h2/h2n
    float* Bbuf = ws + p; p += (size_t)B_ * D_;    // encoded -> qh
    float* Cbuf = ws + p; p += (size_t)B_ * XD_;   // q -> x
    float* Kbuf = ws + p; p += (size_t)M_ * D_;    // k proj -> list/cnt (int)
    float* Vbuf = ws + p; p += (size_t)M_ * D_;    // v proj
    float* Fbuf = ws + p; p += (size_t)B_ * D_;    // fused
    float* Sbuf = ws + p;                          // scores chunk
    size_t availf = (ws_size / 4 > p) ? (ws_size / 4 - p) : 0;
    long long chl = (long long)(availf / 8000);
    int CH = (int)((chl > B_) ? B_ : chl);
    CH &= ~127;
    if (CH < 128) CH = 128;   // minimum viable chunk

    const dim3 blk(256);

    // 1. h = relu(obs @ enc_w1^T + enc_b1) -> Abuf
    gemm_kernel<true, true, false><<<dim3(cdiv(D_,64), cdiv(B_,128), 1), blk, 0, stream>>>(
        obs, enc_w1, enc_b1, nullptr, Abuf, B_, D_, D_, D_, D_, D_, 0, 0, 0, 0.f, 0.f);
    // 2. LN in place
    layernorm_kernel<<<dim3(cdiv(B_,4)), blk, 0, stream>>>(Abuf, enc_g, enc_be, B_);
    // 3. encoded = hn @ enc_w2^T + enc_b2 -> Bbuf
    gemm_kernel<true, false, false><<<dim3(cdiv(D_,64), cdiv(B_,128), 1), blk, 0, stream>>>(
        Abuf, enc_w2, enc_b2, nullptr, Bbuf, B_, D_, D_, D_, D_, D_, 0, 0, 0, 0.f, 0.f);
    // 4. q = encoded @ wq^T + bq -> Cbuf (ld D_)
    gemm_kernel<true, false, false><<<dim3(cdiv(D_,64), cdiv(B_,128), 1), blk, 0, stream>>>(
        Bbuf, wq, bq, nullptr, Cbuf, B_, D_, D_, D_, D_, D_, 0, 0, 0, 0.f, 0.f);
    // 5/6. k/v projections of memory bank
    gemm_kernel<true, false, false><<<dim3(cdiv(D_,64), cdiv(M_,128), 1), blk, 0, stream>>>(
        wmem, wk, bk, nullptr, Kbuf, M_, D_, D_, D_, D_, D_, 0, 0, 0, 0.f, 0.f);
    gemm_kernel<true, false, false><<<dim3(cdiv(D_,64), cdiv(M_,128), 1), blk, 0, stream>>>(
        wmem, wv, bvv, nullptr, Vbuf, M_, D_, D_, D_, D_, D_, 0, 0, 0, 0.f, 0.f);

    // 7-9. attention in batch chunks of CH rows
    for (int r0 = 0; r0 < B_; r0 += CH) {
        const int cha = (B_ - r0 < CH) ? (B_ - r0) : CH;
        // scores[b,h,m] = q[b,h,:] . k[m,h,:]   (scale applied in softmax)
        gemm_kernel<true, false, false><<<dim3(cdiv(M_,64), cdiv(cha,128), H_), blk, 0, stream>>>(
            Cbuf + (long long)r0 * D_, Kbuf, nullptr, nullptr, Sbuf,
            cha, M_, DH_, D_, D_, 8000, DH_, DH_, 1000, 0.f, 0.f);
        softmax_kernel<<<dim3(cdiv(cha * H_, 4)), blk, 0, stream>>>(Sbuf, cha * H_);
        // ctx[b,h,:] = attn[b,h,:] @ v[:,h,:]  -> Abuf
        gemm_kernel<false, false, false><<<dim3(1, cdiv(cha,128), H_), blk, 0, stream>>>(
            Sbuf, Vbuf, nullptr, nullptr, Abuf + (long long)r0 * D_,
            cha, DH_, M_, 8000, D_, D_, 1000, DH_, DH_, 0.f, 0.f);
    }

    // 10. fused = 0.7*encoded + 0.3*(ctx @ wo^T + bo) -> Fbuf
    gemm_kernel<true, false, true><<<dim3(cdiv(D_,64), cdiv(B_,128), 1), blk, 0, stream>>>(
        Abuf, wo, bo, Bbuf, Fbuf, B_, D_, D_, D_, D_, D_, 0, 0, 0, 0.7f, 0.3f);
    // 11. x = concat(fused, ego) -> Cbuf
    concat_kernel<<<dim3(cdiv(B_ * XD_, 256)), blk, 0, stream>>>(Fbuf, ego, Cbuf);
    // 12. h2 = relu(x @ tr_w1^T + tr_b1) -> Abuf
    gemm_kernel<true, true, false><<<dim3(cdiv(D_,64), cdiv(B_,128), 1), blk, 0, stream>>>(
        Cbuf, tr_w1, tr_b1, nullptr, Abuf, B_, D_, XD_, XD_, XD_, D_, 0, 0, 0, 0.f, 0.f);
    // 13. LN in place
    layernorm_kernel<<<dim3(cdiv(B_,4)), blk, 0, stream>>>(Abuf, tr_g, tr_be, B_);
    // 14. next_state = h2n @ tr_w2^T + tr_b2 -> d_out
    gemm_kernel<true, false, false><<<dim3(cdiv(D_,64), cdiv(B_,128), 1), blk, 0, stream>>>(
        Abuf, tr_w2, tr_b2, nullptr, out_ns, B_, D_, D_, D_, D_, D_, 0, 0, 0, 0.f, 0.f);
    // 15. qh = relu(next_state @ q_w1^T + q_b1) -> Bbuf (ld 128)
    gemm_kernel<true, true, false><<<dim3(cdiv(128,64), cdiv(B_,128), 1), blk, 0, stream>>>(
        out_ns, q_w1, q_b1, nullptr, Bbuf, B_, 128, D_, D_, D_, 128, 0, 0, 0, 0.f, 0.f);
    // 16. quality -> d_out segment
    quality_kernel<<<dim3(cdiv(B_,4)), blk, 0, stream>>>(Bbuf, q_w2, q_b2, out_q, B_);
    // 17. ordered compaction of masked rows
    int* list = (int*)Kbuf;
    int* cnt  = list + B_;
    compact_kernel<<<dim3(1), dim3(1024), 0, stream>>>(out_q, list, cnt);
    // 18. scatter-EMA memory update -> d_out segment
    update_memory_kernel<<<dim3(M_), dim3(128), 0, stream>>>(
        wmem, out_ns, upd, list, cnt, out_mem);
}

// Round 2
// 361.329 us; speedup vs baseline: 3.9097x; 3.9097x over previous
//
#include <hip/hip_runtime.h>

#define B_ 8192
#define D_ 512
#define M_ 1000
#define H_ 8

typedef unsigned short u16;
typedef __attribute__((ext_vector_type(8))) short bf16x8;
typedef __attribute__((ext_vector_type(4))) float f32x4;

static inline int cdiv(int a, int b) { return (a + b - 1) / b; }

__device__ __forceinline__ float bf2f(u16 u) {
    union { unsigned u; float f; } c; c.u = ((unsigned)u) << 16; return c.f;
}
__device__ __forceinline__ u16 f2bf(float f) {
    union { float f; unsigned u; } c; c.f = f;
    unsigned r = (c.u + 0x7fffu + ((c.u >> 16) & 1u)) >> 16;
    return (u16)r;
}
__device__ __forceinline__ float wave_sum(float v) {
#pragma unroll
    for (int off = 32; off > 0; off >>= 1) v += __shfl_xor(v, off);
    return v;
}

// ---------------------------------------------------------------------------
// bf16 MFMA GEMM: C = epi(A @ W^T + bias). A[M,K] bf16 row-major, W[N,K] bf16
// row-major. BM=BN=128, BK=64. 4 waves, each 64x64 output (4x4 MFMA tiles).
// LDS: row = 64 bf16 (128B), 8 chunks of 16B, chunk XOR-swizzled by (row&7)
// so ds_read_b128 fragment reads are 2-way (free) and global_load_lds keeps
// its contiguous lane->base+l*16 mapping.
// ---------------------------------------------------------------------------
template<bool RELU, bool COMBINE, bool WF32>
__launch_bounds__(256)
__global__ void mgemm(const u16* __restrict__ A, const u16* __restrict__ W,
                      const float* __restrict__ bias,
                      const u16* __restrict__ E, int ldE, float c0, float c1,
                      float* __restrict__ Cf, u16* __restrict__ Cb,
                      int M, int N, int K, int lda, int ldw, int ldc)
{
    __shared__ u16 As[128 * 64];
    __shared__ u16 Bs[128 * 64];
    const int t = threadIdx.x, w = t >> 6, l = t & 63;
    const int m0 = blockIdx.y * 128, n0 = blockIdx.x * 128;
    const int wm = (w >> 1) * 64, wn = (w & 1) * 64;

    f32x4 acc[4][4];
#pragma unroll
    for (int i = 0; i < 4; ++i)
#pragma unroll
        for (int j = 0; j < 4; ++j) acc[i][j] = (f32x4){0.f, 0.f, 0.f, 0.f};

    const int slot = l & 7;

    for (int k0 = 0; k0 < K; k0 += 64) {
#pragma unroll
        for (int i = 0; i < 4; ++i) {
            const int rl = w * 32 + i * 8 + (l >> 3);      // tile row 0..127
            const int ck = slot ^ (rl & 7);                // swizzled src chunk
            int ga = m0 + rl; ga = ga < M ? ga : M - 1;
            int gb = n0 + rl; gb = gb < N ? gb : N - 1;
            const u16* pa = A + (size_t)ga * lda + k0 + ck * 8;
            const u16* pb = W + (size_t)gb * ldw + k0 + ck * 8;
            __builtin_amdgcn_global_load_lds(
                (const __attribute__((address_space(1))) void*)pa,
                (__attribute__((address_space(3))) void*)(As + (w * 32 + i * 8) * 64),
                16, 0, 0);
            __builtin_amdgcn_global_load_lds(
                (const __attribute__((address_space(1))) void*)pb,
                (__attribute__((address_space(3))) void*)(Bs + (w * 32 + i * 8) * 64),
                16, 0, 0);
        }
        __syncthreads();
#pragma unroll
        for (int ks = 0; ks < 2; ++ks) {
            bf16x8 af[4], bfr[4];
            const int ch = ks * 4 + (l >> 4);
#pragma unroll
            for (int mt = 0; mt < 4; ++mt) {
                const int r = wm + mt * 16 + (l & 15);
                af[mt] = *(const bf16x8*)(As + r * 64 + ((ch ^ (r & 7)) * 8));
            }
#pragma unroll
            for (int nt = 0; nt < 4; ++nt) {
                const int r = wn + nt * 16 + (l & 15);
                bfr[nt] = *(const bf16x8*)(Bs + r * 64 + ((ch ^ (r & 7)) * 8));
            }
#pragma unroll
            for (int mt = 0; mt < 4; ++mt)
#pragma unroll
                for (int nt = 0; nt < 4; ++nt)
                    acc[mt][nt] = __builtin_amdgcn_mfma_f32_16x16x32_bf16(
                        af[mt], bfr[nt], acc[mt][nt], 0, 0, 0);
        }
        __syncthreads();
    }

    float bv[4];
#pragma unroll
    for (int nt = 0; nt < 4; ++nt) bv[nt] = bias[n0 + wn + nt * 16 + (l & 15)];
#pragma unroll
    for (int mt = 0; mt < 4; ++mt) {
#pragma unroll
        for (int r = 0; r < 4; ++r) {
            const int row = m0 + wm + mt * 16 + (l >> 4) * 4 + r;
            if (row >= M) continue;
#pragma unroll
            for (int nt = 0; nt < 4; ++nt) {
                const int col = n0 + wn + nt * 16 + (l & 15);
                float v = acc[mt][nt][r] + bv[nt];
                if (RELU) v = fmaxf(v, 0.f);
                if (COMBINE) v = c0 * bf2f(E[(size_t)row * ldE + col]) + c1 * v;
                Cb[(size_t)row * ldc + col] = f2bf(v);
                if (WF32) Cf[(size_t)row * ldc + col] = v;
            }
        }
    }
}

// ---------------------------------------------------------------------------
// Fused flash attention. Block = 128 queries x 1 head (4 waves x 32 rows).
// S = Q K^T in MFMA C-layout; online softmax; P -> per-wave LDS (swizzled)
// -> A-operand; O += P V via VT (pre-transposed, zero-padded keys>=1000).
// No __syncthreads needed: P is private per wave.
// ---------------------------------------------------------------------------
__launch_bounds__(256)
__global__ void attn_kernel(const u16* __restrict__ Q, const u16* __restrict__ Kb,
                            const u16* __restrict__ VT, u16* __restrict__ O)
{
    __shared__ u16 P[4 * 32 * 64];
    const int t = threadIdx.x, w = t >> 6, l = t & 63;
    const int h = blockIdx.y;
    const int q0 = blockIdx.x * 128 + w * 32;
    u16* Pw = P + w * 2048;

    bf16x8 aq[2][2];
#pragma unroll
    for (int mt = 0; mt < 2; ++mt)
#pragma unroll
        for (int ks = 0; ks < 2; ++ks) {
            const int row = q0 + mt * 16 + (l & 15);
            aq[mt][ks] = *(const bf16x8*)(Q + (size_t)row * 512 + h * 64 + ks * 32 + (l >> 4) * 8);
        }

    f32x4 oacc[2][4];
    float mst[2][4], lst[2][4];
#pragma unroll
    for (int mt = 0; mt < 2; ++mt) {
#pragma unroll
        for (int nt = 0; nt < 4; ++nt) oacc[mt][nt] = (f32x4){0.f, 0.f, 0.f, 0.f};
#pragma unroll
        for (int r = 0; r < 4; ++r) { mst[mt][r] = -3.0e38f; lst[mt][r] = 0.f; }
    }

    for (int kc = 0; kc < 1024; kc += 64) {
        f32x4 s[2][4];
#pragma unroll
        for (int mt = 0; mt < 2; ++mt)
#pragma unroll
            for (int nt = 0; nt < 4; ++nt) s[mt][nt] = (f32x4){0.f, 0.f, 0.f, 0.f};

#pragma unroll
        for (int ks = 0; ks < 2; ++ks) {
            bf16x8 bk[4];
#pragma unroll
            for (int nt = 0; nt < 4; ++nt) {
                const int key = kc + nt * 16 + (l & 15);
                bk[nt] = *(const bf16x8*)(Kb + (size_t)key * 512 + h * 64 + ks * 32 + (l >> 4) * 8);
            }
#pragma unroll
            for (int mt = 0; mt < 2; ++mt)
#pragma unroll
                for (int nt = 0; nt < 4; ++nt)
                    s[mt][nt] = __builtin_amdgcn_mfma_f32_16x16x32_bf16(
                        aq[mt][ks], bk[nt], s[mt][nt], 0, 0, 0);
        }
        // scale + key mask (overwrite, so poison/NaN in padded K rows dies here)
        bool val4[4];
#pragma unroll
        for (int nt = 0; nt < 4; ++nt) val4[nt] = (kc + nt * 16 + (l & 15)) < M_;
#pragma unroll
        for (int mt = 0; mt < 2; ++mt)
#pragma unroll
            for (int nt = 0; nt < 4; ++nt)
#pragma unroll
                for (int r = 0; r < 4; ++r)
                    s[mt][nt][r] = val4[nt] ? s[mt][nt][r] * 0.125f : -3.0e38f;

#pragma unroll
        for (int mt = 0; mt < 2; ++mt) {
            float al[4];
#pragma unroll
            for (int r = 0; r < 4; ++r) {
                float mx = fmaxf(fmaxf(s[mt][0][r], s[mt][1][r]),
                                 fmaxf(s[mt][2][r], s[mt][3][r]));
#pragma unroll
                for (int off = 1; off < 16; off <<= 1) mx = fmaxf(mx, __shfl_xor(mx, off));
                const float mn = fmaxf(mst[mt][r], mx);
                al[r] = __expf(mst[mt][r] - mn);
                mst[mt][r] = mn;
            }
            float rs[4] = {0.f, 0.f, 0.f, 0.f};
#pragma unroll
            for (int nt = 0; nt < 4; ++nt) {
                const int col = nt * 16 + (l & 15);
#pragma unroll
                for (int r = 0; r < 4; ++r) {
                    const float p = __expf(s[mt][nt][r] - mst[mt][r]);
                    rs[r] += p;
                    const int rowl = mt * 16 + (l >> 4) * 4 + r;
                    Pw[rowl * 64 + (((col >> 3) ^ (rowl & 7)) * 8) + (col & 7)] = f2bf(p);
                }
            }
#pragma unroll
            for (int r = 0; r < 4; ++r) {
                float sum = rs[r];
#pragma unroll
                for (int off = 1; off < 16; off <<= 1) sum += __shfl_xor(sum, off);
                lst[mt][r] = lst[mt][r] * al[r] + sum;
#pragma unroll
                for (int nt = 0; nt < 4; ++nt) oacc[mt][nt][r] *= al[r];
            }
        }
        // O += P @ V
#pragma unroll
        for (int ks = 0; ks < 2; ++ks) {
            bf16x8 ap[2], bvv[4];
            const int ch = ks * 4 + (l >> 4);
#pragma unroll
            for (int mt = 0; mt < 2; ++mt) {
                const int rowl = mt * 16 + (l & 15);
                ap[mt] = *(const bf16x8*)(Pw + rowl * 64 + ((ch ^ (rowl & 7)) * 8));
            }
#pragma unroll
            for (int nt = 0; nt < 4; ++nt) {
                const int dh = nt * 16 + (l & 15);
                bvv[nt] = *(const bf16x8*)(VT + ((size_t)(h * 64 + dh)) * 1024 + kc + ks * 32 + (l >> 4) * 8);
            }
#pragma unroll
            for (int mt = 0; mt < 2; ++mt)
#pragma unroll
                for (int nt = 0; nt < 4; ++nt)
                    oacc[mt][nt] = __builtin_amdgcn_mfma_f32_16x16x32_bf16(
                        ap[mt], bvv[nt], oacc[mt][nt], 0, 0, 0);
        }
    }
#pragma unroll
    for (int mt = 0; mt < 2; ++mt)
#pragma unroll
        for (int r = 0; r < 4; ++r) {
            const int row = q0 + mt * 16 + (l >> 4) * 4 + r;
            const float inv = 1.0f / lst[mt][r];
#pragma unroll
            for (int nt = 0; nt < 4; ++nt)
                O[(size_t)row * 512 + h * 64 + nt * 16 + (l & 15)] =
                    f2bf(oacc[mt][nt][r] * inv);
        }
}

// rowwise LayerNorm, bf16 in/out, fp32 math; one wave per 512-col row
__launch_bounds__(256)
__global__ void ln_bf(u16* __restrict__ X, const float* __restrict__ g,
                      const float* __restrict__ be, int rows)
{
    const int row = blockIdx.x * 4 + (threadIdx.x >> 6);
    const int lane = threadIdx.x & 63;
    if (row >= rows) return;
    u16* p = X + (size_t)row * 512 + lane * 8;
    uint4 d = *(const uint4*)p;
    const unsigned dd[4] = {d.x, d.y, d.z, d.w};
    float v[8];
#pragma unroll
    for (int i = 0; i < 4; ++i) {
        v[2 * i]     = bf2f((u16)(dd[i] & 0xffffu));
        v[2 * i + 1] = bf2f((u16)(dd[i] >> 16));
    }
    float s = 0.f;
#pragma unroll
    for (int i = 0; i < 8; ++i) s += v[i];
    s = wave_sum(s);
    const float mu = s * (1.0f / 512.0f);
    float vs = 0.f;
#pragma unroll
    for (int i = 0; i < 8; ++i) { v[i] -= mu; vs += v[i] * v[i]; }
    vs = wave_sum(vs);
    const float r = rsqrtf(vs * (1.0f / 512.0f) + 1e-5f);
    const float* gp = g + lane * 8;
    const float* bp = be + lane * 8;
    unsigned o[4];
#pragma unroll
    for (int i = 0; i < 4; ++i) {
        const u16 lo = f2bf(v[2 * i] * r * gp[2 * i] + bp[2 * i]);
        const u16 hi = f2bf(v[2 * i + 1] * r * gp[2 * i + 1] + bp[2 * i + 1]);
        o[i] = (unsigned)lo | ((unsigned)hi << 16);
    }
    *(uint4*)p = make_uint4(o[0], o[1], o[2], o[3]);
}

// V[1000(pad 1024),512] bf16 -> VT[8][64][1024] bf16, zero for key>=1000
__launch_bounds__(256)
__global__ void vtrans(const u16* __restrict__ V, u16* __restrict__ VT)
{
    __shared__ u16 tile[64][65];
    const int h = blockIdx.y;
    const int k0 = blockIdx.x * 64;
    const int t = threadIdx.x;
#pragma unroll
    for (int i = 0; i < 16; ++i) {
        const int idx = t + i * 256;
        const int r = idx >> 6, c = idx & 63;
        const int key = k0 + r;
        tile[r][c] = (key < M_) ? V[(size_t)key * 512 + h * 64 + c] : (u16)0;
    }
    __syncthreads();
#pragma unroll
    for (int i = 0; i < 16; ++i) {
        const int idx = t + i * 256;
        const int c = idx >> 6, r = idx & 63;
        VT[((size_t)(h * 64 + c)) * 1024 + k0 + r] = tile[r][c];
    }
}

// fp32 -> bf16, n multiple of 4
__global__ void convs(const float* __restrict__ s, u16* __restrict__ d, int n4)
{
    const int i = blockIdx.x * 256 + threadIdx.x;
    if (i >= n4) return;
    const float4 v = ((const float4*)s)[i];
    ushort4 o;
    o.x = f2bf(v.x); o.y = f2bf(v.y); o.z = f2bf(v.z); o.w = f2bf(v.w);
    ((ushort4*)d)[i] = o;
}

// all 9 weight tensors -> bf16; seg 8 = tr_w1 [512,528] -> [512,576] zero-pad
__global__ void convw(const float* s0, const float* s1, const float* s2,
                      const float* s3, const float* s4, const float* s5,
                      const float* s6, const float* s7, const float* s8,
                      u16* d0, u16* d1, u16* d2, u16* d3, u16* d4,
                      u16* d5, u16* d6, u16* d7, u16* d8)
{
    const int seg = blockIdx.y;
    const float* s; u16* d; int n;
    switch (seg) {
        case 0: s = s0; d = d0; n = 262144; break;
        case 1: s = s1; d = d1; n = 262144; break;
        case 2: s = s2; d = d2; n = 262144; break;
        case 3: s = s3; d = d3; n = 262144; break;
        case 4: s = s4; d = d4; n = 262144; break;
        case 5: s = s5; d = d5; n = 262144; break;
        case 6: s = s6; d = d6; n = 262144; break;
        case 7: s = s7; d = d7; n = 65536;  break;
        default: s = s8; d = d8; n = 294912; break;
    }
    const int i0 = (blockIdx.x * 256 + threadIdx.x) * 4;
    if (seg == 8) {
#pragma unroll
        for (int k = 0; k < 4; ++k) {
            const int i = i0 + k;
            if (i < n) {
                const int r = i / 576, c = i - r * 576;
                d[i] = (c < 528) ? f2bf(s[r * 528 + c]) : (u16)0;
            }
        }
    } else if (i0 + 3 < n) {
        const float4 v = *(const float4*)(s + i0);
        ushort4 o;
        o.x = f2bf(v.x); o.y = f2bf(v.y); o.z = f2bf(v.z); o.w = f2bf(v.w);
        *(ushort4*)(d + i0) = o;
    }
}

// xbuf[b][512..575]: ego bf16 then zeros (cols 0..511 written later by wo-GEMM)
__global__ void fillx(const float* __restrict__ ego, u16* __restrict__ xb)
{
    const int i = blockIdx.x * 256 + threadIdx.x;  // 8192*64
    const int b = i >> 6, j = i & 63;
    xb[(size_t)b * 576 + 512 + j] = (j < 16) ? f2bf(ego[b * 16 + j]) : (u16)0;
}

// quality[b] = sigmoid(dot(qh[b,:128], w2) + b2), qh bf16
__global__ void quality_bf(const u16* __restrict__ qh, const float* __restrict__ w2,
                           const float* __restrict__ b2, float* __restrict__ outq,
                           int rows)
{
    const int row = blockIdx.x * 4 + (threadIdx.x >> 6);
    const int lane = threadIdx.x & 63;
    if (row >= rows) return;
    const u16* p = qh + (size_t)row * 128;
    float s = bf2f(p[lane]) * w2[lane] + bf2f(p[64 + lane]) * w2[64 + lane];
    s = wave_sum(s);
    if (lane == 0) outq[row] = 1.0f / (1.0f + expf(-(s + b2[0])));
}

// ordered compaction of {b : quality[b] > 0.7}
__global__ void compact_kernel(const float* __restrict__ q,
                               int* __restrict__ list, int* __restrict__ cnt)
{
    __shared__ int wtot[16];
    __shared__ int sbase;
    const int t = threadIdx.x, w = t >> 6, lane = t & 63;
    if (t == 0) sbase = 0;
    __syncthreads();
    for (int c = 0; c < B_; c += 1024) {
        const int idx = c + t;
        const bool pred = (q[idx] > 0.7f);
        const unsigned long long bal = __ballot(pred);
        const int prefix = __popcll(bal & ((1ull << lane) - 1ull));
        if (lane == 0) wtot[w] = __popcll(bal);
        __syncthreads();
        int woff = 0;
        for (int i = 0; i < w; ++i) woff += wtot[i];
        if (pred) list[sbase + woff + prefix] = idx;
        __syncthreads();
        if (t == 0) {
            int tot = 0;
            for (int i = 0; i < 16; ++i) tot += wtot[i];
            sbase += tot;
        }
        __syncthreads();
    }
    if (t == 0) *cnt = sbase;
}

// scatter-EMA (fp32, order-faithful): one block per memory row
__global__ void update_memory_kernel(const float* __restrict__ mem,
                                     const float* __restrict__ ns,
                                     const int* __restrict__ upd,
                                     const int* __restrict__ list,
                                     const int* __restrict__ cnt,
                                     float* __restrict__ outmem)
{
    const int m = blockIdx.x;
    const int t = threadIdx.x;
    const int c4 = t * 4;
    float4 r = *(const float4*)(mem + (size_t)m * D_ + c4);
    const int n = *cnt;
    for (int i = 0; i < n; ++i) {
        const int b = list[i];
        if (upd[b] == m) {
            const float4 s = *(const float4*)(ns + (size_t)b * D_ + c4);
            r.x = 0.9f * r.x + 0.1f * s.x;
            r.y = 0.9f * r.y + 0.1f * s.y;
            r.z = 0.9f * r.z + 0.1f * s.z;
            r.w = 0.9f * r.w + 0.1f * s.w;
        }
    }
    *(float4*)(outmem + (size_t)m * D_ + c4) = r;
}

extern "C" void kernel_launch(void* const* d_in, const int* in_sizes, int n_in,
                              void* d_out, int out_size, void* d_ws, size_t ws_size,
                              hipStream_t stream)
{
    const float* obs    = (const float*)d_in[0];
    const float* ego    = (const float*)d_in[1];
    const float* wmem   = (const float*)d_in[2];
    const float* enc_w1 = (const float*)d_in[3];
    const float* enc_b1 = (const float*)d_in[4];
    const float* enc_g  = (const float*)d_in[5];
    const float* enc_be = (const float*)d_in[6];
    const float* enc_w2 = (const float*)d_in[7];
    const float* enc_b2 = (const float*)d_in[8];
    const float* wq = (const float*)d_in[9];
    const float* bq = (const float*)d_in[10];
    const float* wk = (const float*)d_in[11];
    const float* bk = (const float*)d_in[12];
    const float* wv = (const float*)d_in[13];
    const float* bvv = (const float*)d_in[14];
    const float* wo = (const float*)d_in[15];
    const float* bo = (const float*)d_in[16];
    const float* tr_w1 = (const float*)d_in[17];
    const float* tr_b1 = (const float*)d_in[18];
    const float* tr_g  = (const float*)d_in[19];
    const float* tr_be = (const float*)d_in[20];
    const float* tr_w2 = (const float*)d_in[21];
    const float* tr_b2 = (const float*)d_in[22];
    const float* q_w1 = (const float*)d_in[23];
    const float* q_b1 = (const float*)d_in[24];
    const float* q_w2 = (const float*)d_in[25];
    const float* q_b2 = (const float*)d_in[26];
    const int*   upd  = (const int*)d_in[27];

    float* out_ns  = (float*)d_out;
    float* out_q   = out_ns + (size_t)B_ * D_;
    float* out_mem = out_q + B_;

    u16* ws = (u16*)d_ws;
    size_t o = 0;
    u16* obs_bf  = ws + o; o += (size_t)B_ * 512;
    u16* wmem_bf = ws + o; o += (size_t)1024 * 512;
    u16* w_enc1  = ws + o; o += 262144;
    u16* w_enc2  = ws + o; o += 262144;
    u16* w_q     = ws + o; o += 262144;
    u16* w_k     = ws + o; o += 262144;
    u16* w_v     = ws + o; o += 262144;
    u16* w_o     = ws + o; o += 262144;
    u16* w_tr2   = ws + o; o += 262144;
    u16* w_qh    = ws + o; o += 65536;
    u16* w_tr1   = ws + o; o += (size_t)512 * 576;
    u16* hbuf    = ws + o; o += (size_t)B_ * 512;
    u16* enc_bf  = ws + o; o += (size_t)B_ * 512;
    u16* qbuf    = ws + o; o += (size_t)B_ * 512;
    u16* Kbuf    = ws + o; o += (size_t)1024 * 512;
    u16* Vbuf    = ws + o; o += (size_t)1024 * 512;
    u16* VTb     = ws + o; o += (size_t)512 * 1024;
    u16* ctx     = ws + o; o += (size_t)B_ * 512;
    u16* xbuf    = ws + o; o += (size_t)B_ * 576;
    u16* nsbf    = ws + o; o += (size_t)B_ * 512;
    u16* qhb     = ws + o; o += (size_t)B_ * 128;
    int* list    = (int*)(ws + o);
    int* cnt     = list + B_;

    const dim3 blk(256);

    // input/weight conversion
    convs<<<dim3(4096), blk, 0, stream>>>(obs, obs_bf, B_ * 512 / 4);
    convs<<<dim3(500),  blk, 0, stream>>>(wmem, wmem_bf, M_ * 512 / 4);
    convw<<<dim3(288, 9), blk, 0, stream>>>(enc_w1, enc_w2, wq, wk, wv, wo, tr_w2,
                                            q_w1, tr_w1,
                                            w_enc1, w_enc2, w_q, w_k, w_v, w_o,
                                            w_tr2, w_qh, w_tr1);
    fillx<<<dim3(2048), blk, 0, stream>>>(ego, xbuf);

    // encoder
    mgemm<true,  false, false><<<dim3(4, 64), blk, 0, stream>>>(
        obs_bf, w_enc1, enc_b1, nullptr, 0, 0.f, 0.f, nullptr, hbuf,
        B_, 512, 512, 512, 512, 512);
    ln_bf<<<dim3(2048), blk, 0, stream>>>(hbuf, enc_g, enc_be, B_);
    mgemm<false, false, false><<<dim3(4, 64), blk, 0, stream>>>(
        hbuf, w_enc2, enc_b2, nullptr, 0, 0.f, 0.f, nullptr, enc_bf,
        B_, 512, 512, 512, 512, 512);

    // projections
    mgemm<false, false, false><<<dim3(4, 64), blk, 0, stream>>>(
        enc_bf, w_q, bq, nullptr, 0, 0.f, 0.f, nullptr, qbuf,
        B_, 512, 512, 512, 512, 512);
    mgemm<false, false, false><<<dim3(4, 8), blk, 0, stream>>>(
        wmem_bf, w_k, bk, nullptr, 0, 0.f, 0.f, nullptr, Kbuf,
        M_, 512, 512, 512, 512, 512);
    mgemm<false, false, false><<<dim3(4, 8), blk, 0, stream>>>(
        wmem_bf, w_v, bvv, nullptr, 0, 0.f, 0.f, nullptr, Vbuf,
        M_, 512, 512, 512, 512, 512);
    vtrans<<<dim3(16, 8), blk, 0, stream>>>(Vbuf, VTb);

    // fused attention
    attn_kernel<<<dim3(64, 8), blk, 0, stream>>>(qbuf, Kbuf, VTb, ctx);

    // out-proj + fuse: xbuf[:, :512] = 0.7*encoded + 0.3*(ctx@wo^T+bo)
    mgemm<false, true, false><<<dim3(4, 64), blk, 0, stream>>>(
        ctx, w_o, bo, enc_bf, 512, 0.7f, 0.3f, nullptr, xbuf,
        B_, 512, 512, 512, 512, 576);

    // transition
    mgemm<true,  false, false><<<dim3(4, 64), blk, 0, stream>>>(
        xbuf, w_tr1, tr_b1, nullptr, 0, 0.f, 0.f, nullptr, hbuf,
        B_, 512, 576, 576, 576, 512);
    ln_bf<<<dim3(2048), blk, 0, stream>>>(hbuf, tr_g, tr_be, B_);
    mgemm<false, false, true><<<dim3(4, 64), blk, 0, stream>>>(
        hbuf, w_tr2, tr_b2, nullptr, 0, 0.f, 0.f, out_ns, nsbf,
        B_, 512, 512, 512, 512, 512);

    // quality head
    mgemm<true,  false, false><<<dim3(1, 64), blk, 0, stream>>>(
        nsbf, w_qh, q_b1, nullptr, 0, 0.f, 0.f, nullptr, qhb,
        B_, 128, 512, 512, 512, 128);
    quality_bf<<<dim3(2048), blk, 0, stream>>>(qhb, q_w2, q_b2, out_q, B_);

    // memory bank scatter-EMA
    compact_kernel<<<dim3(1), dim3(1024), 0, stream>>>(out_q, list, cnt);
    update_memory_kernel<<<dim3(M_), dim3(128), 0, stream>>>(
        wmem, out_ns, upd, list, cnt, out_mem);
}

// Round 3
// 314.909 us; speedup vs baseline: 4.4860x; 1.1474x over previous
//
#include <hip/hip_runtime.h>

#define B_ 8192
#define D_ 512
#define M_ 1000
#define H_ 8

typedef unsigned short u16;
typedef __attribute__((ext_vector_type(8))) short bf16x8;
typedef __attribute__((ext_vector_type(4))) float f32x4;

static inline int cdiv(int a, int b) { return (a + b - 1) / b; }

__device__ __forceinline__ float bf2f(u16 u) {
    union { unsigned u; float f; } c; c.u = ((unsigned)u) << 16; return c.f;
}
// round-to-nearest-even (outputs / weights)
__device__ __forceinline__ u16 f2bf(float f) {
    union { float f; unsigned u; } c; c.f = f;
    unsigned r = (c.u + 0x7fffu + ((c.u >> 16) & 1u)) >> 16;
    return (u16)r;
}
// fast round (hot path, P values >= 0)
__device__ __forceinline__ u16 f2bf_fast(float f) {
    union { float f; unsigned u; } c; c.f = f;
    return (u16)((c.u + 0x8000u) >> 16);
}
__device__ __forceinline__ float wave_sum(float v) {
#pragma unroll
    for (int off = 32; off > 0; off >>= 1) v += __shfl_xor(v, off);
    return v;
}

// ---------------------------------------------------------------------------
// bf16 MFMA GEMM: C = epi(A @ W^T + bias*bscale). A[M,K] bf16, W[N,K] bf16.
// BM=128, BN=64, BK=64. 4 waves, each 32x64 output (2x4 MFMA tiles).
// 512 blocks for the B=8192 GEMMs -> 2 blocks/CU (vs 1 in R2).
// LDS rows are 64 bf16 (128B) in 8 chunks of 16B, XOR-swizzled by (row&7).
// ---------------------------------------------------------------------------
template<bool RELU, bool COMBINE, bool WF32>
__launch_bounds__(256)
__global__ void mgemm(const u16* __restrict__ A, const u16* __restrict__ W,
                      const float* __restrict__ bias, float bscale,
                      const u16* __restrict__ E, int ldE, float c0, float c1,
                      float* __restrict__ Cf, u16* __restrict__ Cb,
                      int M, int N, int K, int lda, int ldw, int ldc)
{
    __shared__ u16 As[128 * 64];
    __shared__ u16 Bs[64 * 64];
    const int t = threadIdx.x, w = t >> 6, l = t & 63;
    const int m0 = blockIdx.y * 128, n0 = blockIdx.x * 64;
    const int wm = w * 32;
    const int li = l & 15, quad = l >> 4;

    f32x4 acc[2][4];
#pragma unroll
    for (int i = 0; i < 2; ++i)
#pragma unroll
        for (int j = 0; j < 4; ++j) acc[i][j] = (f32x4){0.f, 0.f, 0.f, 0.f};

    for (int k0 = 0; k0 < K; k0 += 64) {
#pragma unroll
        for (int i = 0; i < 4; ++i) {
            const int rl = w * 32 + i * 8 + (l >> 3);
            const int ck = (l & 7) ^ (rl & 7);
            int ga = m0 + rl; ga = ga < M ? ga : M - 1;
            __builtin_amdgcn_global_load_lds(
                (const __attribute__((address_space(1))) void*)(A + (size_t)ga * lda + k0 + ck * 8),
                (__attribute__((address_space(3))) void*)(As + (w * 32 + i * 8) * 64),
                16, 0, 0);
        }
#pragma unroll
        for (int i = 0; i < 2; ++i) {
            const int rl = w * 16 + i * 8 + (l >> 3);
            const int ck = (l & 7) ^ (rl & 7);
            int gb = n0 + rl; gb = gb < N ? gb : N - 1;
            __builtin_amdgcn_global_load_lds(
                (const __attribute__((address_space(1))) void*)(W + (size_t)gb * ldw + k0 + ck * 8),
                (__attribute__((address_space(3))) void*)(Bs + (w * 16 + i * 8) * 64),
                16, 0, 0);
        }
        __syncthreads();
#pragma unroll
        for (int ks = 0; ks < 2; ++ks) {
            const int ch = ks * 4 + quad;
            bf16x8 af[2], bfr[4];
#pragma unroll
            for (int mt = 0; mt < 2; ++mt) {
                const int r = wm + mt * 16 + li;
                af[mt] = *(const bf16x8*)(As + r * 64 + ((ch ^ (r & 7)) * 8));
            }
#pragma unroll
            for (int nt = 0; nt < 4; ++nt) {
                const int r = nt * 16 + li;
                bfr[nt] = *(const bf16x8*)(Bs + r * 64 + ((ch ^ (r & 7)) * 8));
            }
#pragma unroll
            for (int mt = 0; mt < 2; ++mt)
#pragma unroll
                for (int nt = 0; nt < 4; ++nt)
                    acc[mt][nt] = __builtin_amdgcn_mfma_f32_16x16x32_bf16(
                        af[mt], bfr[nt], acc[mt][nt], 0, 0, 0);
        }
        __syncthreads();
    }

    float bv[4];
#pragma unroll
    for (int nt = 0; nt < 4; ++nt) bv[nt] = bias[n0 + nt * 16 + li] * bscale;
#pragma unroll
    for (int mt = 0; mt < 2; ++mt) {
#pragma unroll
        for (int r = 0; r < 4; ++r) {
            const int row = m0 + wm + mt * 16 + quad * 4 + r;
            if (row >= M) continue;
#pragma unroll
            for (int nt = 0; nt < 4; ++nt) {
                const int col = n0 + nt * 16 + li;
                float v = acc[mt][nt][r] + bv[nt];
                if (RELU) v = fmaxf(v, 0.f);
                if (COMBINE) v = c0 * bf2f(E[(size_t)row * ldE + col]) + c1 * v;
                Cb[(size_t)row * ldc + col] = f2bf(v);
                if (WF32) Cf[(size_t)row * ldc + col] = v;
            }
        }
    }
}

// ---------------------------------------------------------------------------
// Fused flash attention, no-max softmax (scores bounded; q pre-scaled 1/8).
// Block = 128 queries x 1 head (4 waves x 32 rows). Row-sum l obtained via an
// extra MFMA against a ones B-fragment (no cross-lane reductions at all).
// KV: [1000(+pad) x 1024] rows = keys, cols 0..511 = K-proj, 512.. = V-proj.
// ---------------------------------------------------------------------------
__launch_bounds__(256)
__global__ void attn_kernel(const u16* __restrict__ Q, const u16* __restrict__ KV,
                            const u16* __restrict__ VT, u16* __restrict__ O)
{
    __shared__ u16 P[4 * 2048];
    const int t = threadIdx.x, w = t >> 6, l = t & 63;
    const int h = blockIdx.y;
    const int q0 = blockIdx.x * 128 + w * 32;
    u16* Pw = P + w * 2048;
    const int li = l & 15, quad = l >> 4;

    bf16x8 aq[2][2];
#pragma unroll
    for (int mt = 0; mt < 2; ++mt)
#pragma unroll
        for (int ks = 0; ks < 2; ++ks) {
            const int row = q0 + mt * 16 + li;
            aq[mt][ks] = *(const bf16x8*)(Q + (size_t)row * 512 + h * 64 + ks * 32 + quad * 8);
        }

    bf16x8 ones;
#pragma unroll
    for (int i = 0; i < 8; ++i) ones[i] = (short)0x3F80;   // bf16 1.0

    f32x4 oacc[2][4];
    f32x4 lacc[2];
#pragma unroll
    for (int mt = 0; mt < 2; ++mt) {
        lacc[mt] = (f32x4){0.f, 0.f, 0.f, 0.f};
#pragma unroll
        for (int nt = 0; nt < 4; ++nt) oacc[mt][nt] = (f32x4){0.f, 0.f, 0.f, 0.f};
    }

    for (int kc = 0; kc < 1024; kc += 64) {
        f32x4 s[2][4];
#pragma unroll
        for (int mt = 0; mt < 2; ++mt)
#pragma unroll
            for (int nt = 0; nt < 4; ++nt) s[mt][nt] = (f32x4){0.f, 0.f, 0.f, 0.f};

#pragma unroll
        for (int ks = 0; ks < 2; ++ks) {
            bf16x8 bk[4];
#pragma unroll
            for (int nt = 0; nt < 4; ++nt) {
                const int key = kc + nt * 16 + li;
                bk[nt] = *(const bf16x8*)(KV + (size_t)key * 1024 + h * 64 + ks * 32 + quad * 8);
            }
#pragma unroll
            for (int mt = 0; mt < 2; ++mt)
#pragma unroll
                for (int nt = 0; nt < 4; ++nt)
                    s[mt][nt] = __builtin_amdgcn_mfma_f32_16x16x32_bf16(
                        aq[mt][ks], bk[nt], s[mt][nt], 0, 0, 0);
        }
        if (kc == 960) {   // only the last chunk contains padded keys
#pragma unroll
            for (int nt = 0; nt < 4; ++nt) {
                const bool val = (960 + nt * 16 + li) < M_;
#pragma unroll
                for (int mt = 0; mt < 2; ++mt)
#pragma unroll
                    for (int r = 0; r < 4; ++r)
                        if (!val) s[mt][nt][r] = -3.0e38f;
            }
        }
        // exp + pack to LDS (XOR-swizzled key-minor rows for b128 A-frag reads)
#pragma unroll
        for (int mt = 0; mt < 2; ++mt)
#pragma unroll
            for (int nt = 0; nt < 4; ++nt) {
                const int col = nt * 16 + li;
#pragma unroll
                for (int r = 0; r < 4; ++r) {
                    const float p = __expf(s[mt][nt][r]);
                    const int rowl = mt * 16 + quad * 4 + r;
                    Pw[rowl * 64 + (((col >> 3) ^ (rowl & 7)) * 8) + (col & 7)] = f2bf_fast(p);
                }
            }
        // O += P @ V ; l += P @ ones
#pragma unroll
        for (int ks = 0; ks < 2; ++ks) {
            const int ch = ks * 4 + quad;
            bf16x8 ap[2], bvv[4];
#pragma unroll
            for (int mt = 0; mt < 2; ++mt) {
                const int rowl = mt * 16 + li;
                ap[mt] = *(const bf16x8*)(Pw + rowl * 64 + ((ch ^ (rowl & 7)) * 8));
            }
#pragma unroll
            for (int mt = 0; mt < 2; ++mt)
                lacc[mt] = __builtin_amdgcn_mfma_f32_16x16x32_bf16(
                    ap[mt], ones, lacc[mt], 0, 0, 0);
#pragma unroll
            for (int nt = 0; nt < 4; ++nt) {
                const int dh = nt * 16 + li;
                bvv[nt] = *(const bf16x8*)(VT + ((size_t)(h * 64 + dh)) * 1024 + kc + ks * 32 + quad * 8);
            }
#pragma unroll
            for (int mt = 0; mt < 2; ++mt)
#pragma unroll
                for (int nt = 0; nt < 4; ++nt)
                    oacc[mt][nt] = __builtin_amdgcn_mfma_f32_16x16x32_bf16(
                        ap[mt], bvv[nt], oacc[mt][nt], 0, 0, 0);
        }
    }
#pragma unroll
    for (int mt = 0; mt < 2; ++mt)
#pragma unroll
        for (int r = 0; r < 4; ++r) {
            const int row = q0 + mt * 16 + quad * 4 + r;
            const float inv = 1.0f / lacc[mt][r];
#pragma unroll
            for (int nt = 0; nt < 4; ++nt)
                O[(size_t)row * 512 + h * 64 + nt * 16 + li] =
                    f2bf(oacc[mt][nt][r] * inv);
        }
}

// rowwise LayerNorm, bf16 in/out, fp32 math; one wave per 512-col row
__launch_bounds__(256)
__global__ void ln_bf(u16* __restrict__ X, const float* __restrict__ g,
                      const float* __restrict__ be, int rows)
{
    const int row = blockIdx.x * 4 + (threadIdx.x >> 6);
    const int lane = threadIdx.x & 63;
    if (row >= rows) return;
    u16* p = X + (size_t)row * 512 + lane * 8;
    uint4 d = *(const uint4*)p;
    const unsigned dd[4] = {d.x, d.y, d.z, d.w};
    float v[8];
#pragma unroll
    for (int i = 0; i < 4; ++i) {
        v[2 * i]     = bf2f((u16)(dd[i] & 0xffffu));
        v[2 * i + 1] = bf2f((u16)(dd[i] >> 16));
    }
    float s = 0.f;
#pragma unroll
    for (int i = 0; i < 8; ++i) s += v[i];
    s = wave_sum(s);
    const float mu = s * (1.0f / 512.0f);
    float vs = 0.f;
#pragma unroll
    for (int i = 0; i < 8; ++i) { v[i] -= mu; vs += v[i] * v[i]; }
    vs = wave_sum(vs);
    const float r = rsqrtf(vs * (1.0f / 512.0f) + 1e-5f);
    const float* gp = g + lane * 8;
    const float* bp = be + lane * 8;
    unsigned o[4];
#pragma unroll
    for (int i = 0; i < 4; ++i) {
        const u16 lo = f2bf(v[2 * i] * r * gp[2 * i] + bp[2 * i]);
        const u16 hi = f2bf(v[2 * i + 1] * r * gp[2 * i + 1] + bp[2 * i + 1]);
        o[i] = (unsigned)lo | ((unsigned)hi << 16);
    }
    *(uint4*)p = make_uint4(o[0], o[1], o[2], o[3]);
}

// V columns of KV[1000x1024] -> VT[8][64][1024], zero-padded keys >= 1000
__launch_bounds__(256)
__global__ void vtrans(const u16* __restrict__ KV, u16* __restrict__ VT)
{
    __shared__ u16 tile[64][65];
    const int h = blockIdx.y;
    const int k0 = blockIdx.x * 64;
    const int t = threadIdx.x;
#pragma unroll
    for (int i = 0; i < 16; ++i) {
        const int idx = t + i * 256;
        const int r = idx >> 6, c = idx & 63;
        const int key = k0 + r;
        tile[r][c] = (key < M_) ? KV[(size_t)key * 1024 + 512 + h * 64 + c] : (u16)0;
    }
    __syncthreads();
#pragma unroll
    for (int i = 0; i < 16; ++i) {
        const int idx = t + i * 256;
        const int c = idx >> 6, r = idx & 63;
        VT[((size_t)(h * 64 + c)) * 1024 + k0 + r] = tile[r][c];
    }
}

// all 9 weight tensors -> bf16; seg 2 (wq) scaled 1/8 (attention 1/sqrt(64));
// seg 8 = tr_w1 [512,528] -> [512,576] zero-pad
__global__ void convw(const float* s0, const float* s1, const float* s2,
                      const float* s3, const float* s4, const float* s5,
                      const float* s6, const float* s7, const float* s8,
                      u16* d0, u16* d1, u16* d2, u16* d3, u16* d4,
                      u16* d5, u16* d6, u16* d7, u16* d8)
{
    const int seg = blockIdx.y;
    const float* s; u16* d; int n;
    switch (seg) {
        case 0: s = s0; d = d0; n = 262144; break;
        case 1: s = s1; d = d1; n = 262144; break;
        case 2: s = s2; d = d2; n = 262144; break;
        case 3: s = s3; d = d3; n = 262144; break;
        case 4: s = s4; d = d4; n = 262144; break;
        case 5: s = s5; d = d5; n = 262144; break;
        case 6: s = s6; d = d6; n = 262144; break;
        case 7: s = s7; d = d7; n = 65536;  break;
        default: s = s8; d = d8; n = 294912; break;
    }
    const float sc = (seg == 2) ? 0.125f : 1.0f;
    const int i0 = (blockIdx.x * 256 + threadIdx.x) * 4;
    if (seg == 8) {
#pragma unroll
        for (int k = 0; k < 4; ++k) {
            const int i = i0 + k;
            if (i < n) {
                const int r = i / 576, c = i - r * 576;
                d[i] = (c < 528) ? f2bf(s[r * 528 + c]) : (u16)0;
            }
        }
    } else if (i0 + 3 < n) {
        const float4 v = *(const float4*)(s + i0);
        ushort4 o;
        o.x = f2bf(v.x * sc); o.y = f2bf(v.y * sc);
        o.z = f2bf(v.z * sc); o.w = f2bf(v.w * sc);
        *(ushort4*)(d + i0) = o;
    }
}

// misc prep: obs->bf16, wmem->bf16, xbuf ego-tail fill, fused kv bias
__global__ void prep_misc(const float* __restrict__ obs, const float* __restrict__ wmem,
                          const float* __restrict__ ego, const float* __restrict__ bk,
                          const float* __restrict__ bvv,
                          u16* __restrict__ obs_bf, u16* __restrict__ wmem_bf,
                          u16* __restrict__ xb, float* __restrict__ bkv)
{
    const int seg = blockIdx.y;
    const int tid = blockIdx.x * 256 + threadIdx.x;
    const int nth = gridDim.x * 256;
    if (seg == 0) {
        for (int i = tid; i < B_ * 512 / 4; i += nth) {
            const float4 v = ((const float4*)obs)[i];
            ushort4 o;
            o.x = f2bf(v.x); o.y = f2bf(v.y); o.z = f2bf(v.z); o.w = f2bf(v.w);
            ((ushort4*)obs_bf)[i] = o;
        }
    } else if (seg == 1) {
        for (int i = tid; i < M_ * 512 / 4; i += nth) {
            const float4 v = ((const float4*)wmem)[i];
            ushort4 o;
            o.x = f2bf(v.x); o.y = f2bf(v.y); o.z = f2bf(v.z); o.w = f2bf(v.w);
            ((ushort4*)wmem_bf)[i] = o;
        }
    } else {
        for (int i = tid; i < B_ * 64; i += nth) {
            const int b = i >> 6, j = i & 63;
            xb[(size_t)b * 576 + 512 + j] = (j < 16) ? f2bf(ego[b * 16 + j]) : (u16)0;
        }
        if (tid < 1024) bkv[tid] = (tid < 512) ? bk[tid] : bvv[tid - 512];
    }
}

// quality[b] = sigmoid(dot(qh[b,:128], w2) + b2), qh bf16
__global__ void quality_bf(const u16* __restrict__ qh, const float* __restrict__ w2,
                           const float* __restrict__ b2, float* __restrict__ outq,
                           int rows)
{
    const int row = blockIdx.x * 4 + (threadIdx.x >> 6);
    const int lane = threadIdx.x & 63;
    if (row >= rows) return;
    const u16* p = qh + (size_t)row * 128;
    float s = bf2f(p[lane]) * w2[lane] + bf2f(p[64 + lane]) * w2[64 + lane];
    s = wave_sum(s);
    if (lane == 0) outq[row] = 1.0f / (1.0f + expf(-(s + b2[0])));
}

// ordered compaction of {b : quality[b] > 0.7}
__global__ void compact_kernel(const float* __restrict__ q,
                               int* __restrict__ list, int* __restrict__ cnt)
{
    __shared__ int wtot[16];
    __shared__ int sbase;
    const int t = threadIdx.x, w = t >> 6, lane = t & 63;
    if (t == 0) sbase = 0;
    __syncthreads();
    for (int c = 0; c < B_; c += 1024) {
        const int idx = c + t;
        const bool pred = (q[idx] > 0.7f);
        const unsigned long long bal = __ballot(pred);
        const int prefix = __popcll(bal & ((1ull << lane) - 1ull));
        if (lane == 0) wtot[w] = __popcll(bal);
        __syncthreads();
        int woff = 0;
        for (int i = 0; i < w; ++i) woff += wtot[i];
        if (pred) list[sbase + woff + prefix] = idx;
        __syncthreads();
        if (t == 0) {
            int tot = 0;
            for (int i = 0; i < 16; ++i) tot += wtot[i];
            sbase += tot;
        }
        __syncthreads();
    }
    if (t == 0) *cnt = sbase;
}

// scatter-EMA (fp32, order-faithful): one block per memory row
__global__ void update_memory_kernel(const float* __restrict__ mem,
                                     const float* __restrict__ ns,
                                     const int* __restrict__ upd,
                                     const int* __restrict__ list,
                                     const int* __restrict__ cnt,
                                     float* __restrict__ outmem)
{
    const int m = blockIdx.x;
    const int t = threadIdx.x;
    const int c4 = t * 4;
    float4 r = *(const float4*)(mem + (size_t)m * D_ + c4);
    const int n = *cnt;
    for (int i = 0; i < n; ++i) {
        const int b = list[i];
        if (upd[b] == m) {
            const float4 s = *(const float4*)(ns + (size_t)b * D_ + c4);
            r.x = 0.9f * r.x + 0.1f * s.x;
            r.y = 0.9f * r.y + 0.1f * s.y;
            r.z = 0.9f * r.z + 0.1f * s.z;
            r.w = 0.9f * r.w + 0.1f * s.w;
        }
    }
    *(float4*)(outmem + (size_t)m * D_ + c4) = r;
}

extern "C" void kernel_launch(void* const* d_in, const int* in_sizes, int n_in,
                              void* d_out, int out_size, void* d_ws, size_t ws_size,
                              hipStream_t stream)
{
    const float* obs    = (const float*)d_in[0];
    const float* ego    = (const float*)d_in[1];
    const float* wmem   = (const float*)d_in[2];
    const float* enc_w1 = (const float*)d_in[3];
    const float* enc_b1 = (const float*)d_in[4];
    const float* enc_g  = (const float*)d_in[5];
    const float* enc_be = (const float*)d_in[6];
    const float* enc_w2 = (const float*)d_in[7];
    const float* enc_b2 = (const float*)d_in[8];
    const float* wq = (const float*)d_in[9];
    const float* bq = (const float*)d_in[10];
    const float* wk = (const float*)d_in[11];
    const float* bk = (const float*)d_in[12];
    const float* wv = (const float*)d_in[13];
    const float* bvv = (const float*)d_in[14];
    const float* wo = (const float*)d_in[15];
    const float* bo = (const float*)d_in[16];
    const float* tr_w1 = (const float*)d_in[17];
    const float* tr_b1 = (const float*)d_in[18];
    const float* tr_g  = (const float*)d_in[19];
    const float* tr_be = (const float*)d_in[20];
    const float* tr_w2 = (const float*)d_in[21];
    const float* tr_b2 = (const float*)d_in[22];
    const float* q_w1 = (const float*)d_in[23];
    const float* q_b1 = (const float*)d_in[24];
    const float* q_w2 = (const float*)d_in[25];
    const float* q_b2 = (const float*)d_in[26];
    const int*   upd  = (const int*)d_in[27];

    float* out_ns  = (float*)d_out;
    float* out_q   = out_ns + (size_t)B_ * D_;
    float* out_mem = out_q + B_;

    u16* ws = (u16*)d_ws;
    size_t o = 0;
    u16* obs_bf  = ws + o; o += (size_t)B_ * 512;
    u16* wmem_bf = ws + o; o += (size_t)M_ * 512;
    u16* w_enc1  = ws + o; o += 262144;
    u16* w_enc2  = ws + o; o += 262144;
    u16* w_q     = ws + o; o += 262144;
    u16* w_k     = ws + o; o += 262144;   // w_k || w_v contiguous = fused KV weight
    u16* w_v     = ws + o; o += 262144;
    u16* w_o     = ws + o; o += 262144;
    u16* w_tr2   = ws + o; o += 262144;
    u16* w_qh    = ws + o; o += 65536;
    u16* w_tr1   = ws + o; o += (size_t)512 * 576;
    u16* hbuf    = ws + o; o += (size_t)B_ * 512;
    u16* enc_bf  = ws + o; o += (size_t)B_ * 512;
    u16* qbuf    = ws + o; o += (size_t)B_ * 512;
    u16* KVbuf   = ws + o; o += (size_t)M_ * 1024;  // [key][K|V]
    u16* VTb     = ws + o; o += (size_t)512 * 1024;
    u16* ctx     = ws + o; o += (size_t)B_ * 512;
    u16* xbuf    = ws + o; o += (size_t)B_ * 576;
    u16* nsbf    = ws + o; o += (size_t)B_ * 512;
    u16* qhb     = ws + o; o += (size_t)B_ * 128;
    float* bkv   = (float*)(ws + o); o += 2048;
    int* list    = (int*)(ws + o);
    int* cnt     = list + B_;
    (void)w_v;

    const dim3 blk(256);

    // prep
    convw<<<dim3(288, 9), blk, 0, stream>>>(enc_w1, enc_w2, wq, wk, wv, wo, tr_w2,
                                            q_w1, tr_w1,
                                            w_enc1, w_enc2, w_q, w_k, w_v, w_o,
                                            w_tr2, w_qh, w_tr1);
    prep_misc<<<dim3(1024, 3), blk, 0, stream>>>(obs, wmem, ego, bk, bvv,
                                                 obs_bf, wmem_bf, xbuf, bkv);

    // encoder
    mgemm<true,  false, false><<<dim3(8, 64), blk, 0, stream>>>(
        obs_bf, w_enc1, enc_b1, 1.f, nullptr, 0, 0.f, 0.f, nullptr, hbuf,
        B_, 512, 512, 512, 512, 512);
    ln_bf<<<dim3(2048), blk, 0, stream>>>(hbuf, enc_g, enc_be, B_);
    mgemm<false, false, false><<<dim3(8, 64), blk, 0, stream>>>(
        hbuf, w_enc2, enc_b2, 1.f, nullptr, 0, 0.f, 0.f, nullptr, enc_bf,
        B_, 512, 512, 512, 512, 512);

    // q projection (weights+bias pre-scaled by 1/8 = 1/sqrt(64))
    mgemm<false, false, false><<<dim3(8, 64), blk, 0, stream>>>(
        enc_bf, w_q, bq, 0.125f, nullptr, 0, 0.f, 0.f, nullptr, qbuf,
        B_, 512, 512, 512, 512, 512);
    // fused K|V projection of memory bank -> KVbuf[1000 x 1024]
    mgemm<false, false, false><<<dim3(16, 8), blk, 0, stream>>>(
        wmem_bf, w_k, bkv, 1.f, nullptr, 0, 0.f, 0.f, nullptr, KVbuf,
        M_, 1024, 512, 512, 512, 1024);
    vtrans<<<dim3(16, 8), blk, 0, stream>>>(KVbuf, VTb);

    // fused attention
    attn_kernel<<<dim3(64, 8), blk, 0, stream>>>(qbuf, KVbuf, VTb, ctx);

    // out-proj + fuse: xbuf[:, :512] = 0.7*encoded + 0.3*(ctx@wo^T+bo)
    mgemm<false, true, false><<<dim3(8, 64), blk, 0, stream>>>(
        ctx, w_o, bo, 1.f, enc_bf, 512, 0.7f, 0.3f, nullptr, xbuf,
        B_, 512, 512, 512, 512, 576);

    // transition
    mgemm<true,  false, false><<<dim3(8, 64), blk, 0, stream>>>(
        xbuf, w_tr1, tr_b1, 1.f, nullptr, 0, 0.f, 0.f, nullptr, hbuf,
        B_, 512, 576, 576, 576, 512);
    ln_bf<<<dim3(2048), blk, 0, stream>>>(hbuf, tr_g, tr_be, B_);
    mgemm<false, false, true><<<dim3(8, 64), blk, 0, stream>>>(
        hbuf, w_tr2, tr_b2, 1.f, nullptr, 0, 0.f, 0.f, out_ns, nsbf,
        B_, 512, 512, 512, 512, 512);

    // quality head
    mgemm<true,  false, false><<<dim3(2, 64), blk, 0, stream>>>(
        nsbf, w_qh, q_b1, 1.f, nullptr, 0, 0.f, 0.f, nullptr, qhb,
        B_, 128, 512, 512, 512, 128);
    quality_bf<<<dim3(2048), blk, 0, stream>>>(qhb, q_w2, q_b2, out_q, B_);

    // memory bank scatter-EMA
    compact_kernel<<<dim3(1), dim3(1024), 0, stream>>>(out_q, list, cnt);
    update_memory_kernel<<<dim3(M_), dim3(128), 0, stream>>>(
        wmem, out_ns, upd, list, cnt, out_mem);
}